// Round 1
// baseline (138.007 us; speedup 1.0000x reference)
//
#include <hip/hip_runtime.h>

#define BN 2048
#define BB 4
#define HH 4
#define DD 32
#define KIN 64
#define KOUT 128
#define NEGV -1000000000.0f

// Kernel 1: h = x @ W  (fp32), plus s_src[b,h,n], s_dst[b,h,n]
__global__ __launch_bounds__(128) void lin_kernel(
    const float* __restrict__ x, const float* __restrict__ W,
    const float* __restrict__ a_src, const float* __restrict__ a_dst,
    float* __restrict__ hbuf, float* __restrict__ ssrc, float* __restrict__ sdst) {
  __shared__ float xs[KIN];
  const int row = blockIdx.x;            // b*N + n
  const int c = threadIdx.x;             // 0..127 output column
  if (c < KIN) xs[c] = x[(size_t)row * KIN + c];
  __syncthreads();
  float acc = 0.f;
#pragma unroll
  for (int k = 0; k < KIN; ++k) acc = fmaf(xs[k], W[k * KOUT + c], acc);
  hbuf[(size_t)row * KOUT + c] = acc;
  // per-head dot with a_src/a_dst: reduce within 32-lane (d) groups
  float ps = acc * a_src[c];
  float pd = acc * a_dst[c];
#pragma unroll
  for (int o = 16; o >= 1; o >>= 1) {
    ps += __shfl_xor(ps, o);
    pd += __shfl_xor(pd, o);
  }
  if ((c & 31) == 0) {
    const int head = c >> 5;
    const int b = row >> 11, n = row & (BN - 1);
    ssrc[(b * HH + head) * BN + n] = ps;
    sdst[(b * HH + head) * BN + n] = pd;
  }
}

// Kernel 2: one block per (b, i). Wave w handles head h = w.
// Full softmax over j (max-subtracted) == reference top-k result within fp32
// underflow; only entries with val - max > -30 contribute (>= ~1e-13).
__global__ __launch_bounds__(256) void gat_kernel(
    const float* __restrict__ hbuf, const float* __restrict__ ssrc,
    const float* __restrict__ sdst, const float* __restrict__ mask,
    float* __restrict__ outp, float* __restrict__ amean) {
  const int bi = blockIdx.x;
  const int b = bi >> 11, i = bi & (BN - 1);
  const int lane = threadIdx.x & 63;
  const int h = threadIdx.x >> 6;

  __shared__ float arow[BN];      // per-(b,i) alpha_mean row accumulator
  __shared__ int ls_j[HH][32];
  __shared__ float ls_a[HH][32];
  __shared__ int ls_cnt[HH];

  for (int k = threadIdx.x; k < BN; k += 256) arow[k] = 0.f;
  if (lane == 0) ls_cnt[h] = 0;
  __syncthreads();

  const float s_i = ssrc[(b * HH + h) * BN + i];
  const float* __restrict__ sd = sdst + (b * HH + h) * BN;
  const float* __restrict__ mrow = mask + (size_t)i * BN;

  float val[BN / 64];
  float vmax = -3.0e38f;
#pragma unroll
  for (int t = 0; t < BN / 64; ++t) {
    const int j = t * 64 + lane;
    const float m = mrow[j];
    const float s = s_i + sd[j];
    const float e = (s < 0.f) ? 0.2f * s : s;
    const float v = e * m + (1.0f - m) * NEGV;   // reference formula order
    val[t] = v;
    vmax = fmaxf(vmax, v);
  }
#pragma unroll
  for (int o = 32; o >= 1; o >>= 1) vmax = fmaxf(vmax, __shfl_xor(vmax, o));

  float lsum = 0.f;
#pragma unroll
  for (int t = 0; t < BN / 64; ++t) {
    const float d = val[t] - vmax;
    float ex = 0.f;
    if (d > -30.f) ex = __expf(d);   // whole-wave branch skips expf almost always
    val[t] = ex;
    lsum += ex;
  }
  float sum = lsum;
#pragma unroll
  for (int o = 32; o >= 1; o >>= 1) sum += __shfl_xor(sum, o);
  const float inv = 1.0f / sum;

  // sparse selection: push contributing (j, alpha) to per-head list,
  // accumulate alpha/H into the LDS alpha_mean row
#pragma unroll
  for (int t = 0; t < BN / 64; ++t) {
    if (val[t] > 0.f) {
      const float a = val[t] * inv;
      const int j = t * 64 + lane;
      const int slot = atomicAdd(&ls_cnt[h], 1);
      if (slot < 32) { ls_j[h][slot] = j; ls_a[h][slot] = a; }
      atomicAdd(&arow[j], a * 0.25f);
    }
  }

  // out[b,i,h,:] = sum over selected j of alpha * h[b,j,h,:]
  int cnt = ls_cnt[h];           // wave-local list; same-wave ordering is safe
  if (cnt > 32) cnt = 32;
  const int d = lane & 31;
  const int half = lane >> 5;
  float acc = 0.f;
  for (int k = half; k < cnt; k += 2) {
    const int jj = ls_j[h][k];
    const float aa = ls_a[h][k];
    acc = fmaf(aa, hbuf[((size_t)(b * BN + jj)) * KOUT + h * DD + d], acc);
  }
  acc += __shfl_xor(acc, 32);
  if (half == 0) outp[((size_t)(b * BN + i)) * KOUT + h * DD + d] = acc;

  __syncthreads();
  // stream the completed alpha_mean row to global (coalesced)
  float* __restrict__ arow_g = amean + ((size_t)(b * BN + i)) * BN;
  for (int k = threadIdx.x; k < BN; k += 256) arow_g[k] = arow[k];
}

extern "C" void kernel_launch(void* const* d_in, const int* in_sizes, int n_in,
                              void* d_out, int out_size, void* d_ws, size_t ws_size,
                              hipStream_t stream) {
  const float* x = (const float*)d_in[0];
  const float* W = (const float*)d_in[1];
  const float* a_src = (const float*)d_in[2];
  const float* a_dst = (const float*)d_in[3];
  const float* mask = (const float*)d_in[4];

  float* outp = (float*)d_out;                       // (B,N,H*D)
  float* amean = outp + (size_t)BB * BN * KOUT;      // (B,N,N)

  float* hbuf = (float*)d_ws;                        // (B,N,H*D) fp32
  float* ssrc = hbuf + (size_t)BB * BN * KOUT;       // (B,H,N)
  float* sdst = ssrc + (size_t)BB * HH * BN;         // (B,H,N)

  lin_kernel<<<BB * BN, 128, 0, stream>>>(x, W, a_src, a_dst, hbuf, ssrc, sdst);
  gat_kernel<<<BB * BN, 256, 0, stream>>>(hbuf, ssrc, sdst, mask, outp, amean);
}

// Round 3
// 127.925 us; speedup vs baseline: 1.0788x; 1.0788x over previous
//
#include <hip/hip_runtime.h>

#define BN 2048
#define BB 4
#define HH 4
#define DD 32
#define KIN 64
#define KOUT 128
#define NEGV -1000000000.0f

typedef float nfloat4 __attribute__((ext_vector_type(4)));

// Kernel 1: h = x @ W (fp32) + s_src[b,h,n], s_dst[b,h,n].
// 8 rows per block, W staged in LDS, float4 everywhere.
__global__ __launch_bounds__(256) void lin_kernel(
    const float* __restrict__ x, const float* __restrict__ W,
    const float* __restrict__ a_src, const float* __restrict__ a_dst,
    float* __restrict__ hbuf, float* __restrict__ ssrc, float* __restrict__ sdst) {
  __shared__ float Ws[KIN * KOUT];   // 32 KB
  __shared__ float xs[8][KIN];       // 2 KB
  const int tid = threadIdx.x;
  const int r0 = blockIdx.x * 8;     // global row base (8 | 2048 so same b)

  nfloat4* Ws4 = (nfloat4*)Ws;
  const nfloat4* W4 = (const nfloat4*)W;
#pragma unroll
  for (int t = 0; t < 8; ++t) Ws4[tid + t * 256] = W4[tid + t * 256];
  if (tid < 128) ((nfloat4*)xs)[tid] = ((const nfloat4*)(x + (size_t)r0 * KIN))[tid];
  __syncthreads();

  const int col = tid & 127;
  const int rp = tid >> 7;           // 0..1; rows rp, rp+2, rp+4, rp+6
  float a0 = 0.f, a1 = 0.f, a2 = 0.f, a3 = 0.f;
#pragma unroll
  for (int kk = 0; kk < KIN; kk += 4) {
    const nfloat4 x0 = *(const nfloat4*)&xs[rp][kk];
    const nfloat4 x1 = *(const nfloat4*)&xs[rp + 2][kk];
    const nfloat4 x2 = *(const nfloat4*)&xs[rp + 4][kk];
    const nfloat4 x3 = *(const nfloat4*)&xs[rp + 6][kk];
#pragma unroll
    for (int u = 0; u < 4; ++u) {
      const float w = Ws[(kk + u) * KOUT + col];
      a0 = fmaf(x0[u], w, a0);
      a1 = fmaf(x1[u], w, a1);
      a2 = fmaf(x2[u], w, a2);
      a3 = fmaf(x3[u], w, a3);
    }
  }
  hbuf[(size_t)(r0 + rp + 0) * KOUT + col] = a0;
  hbuf[(size_t)(r0 + rp + 2) * KOUT + col] = a1;
  hbuf[(size_t)(r0 + rp + 4) * KOUT + col] = a2;
  hbuf[(size_t)(r0 + rp + 6) * KOUT + col] = a3;

  const float as = a_src[col], ad = a_dst[col];
  float ps0 = a0 * as, ps1 = a1 * as, ps2 = a2 * as, ps3 = a3 * as;
  float pd0 = a0 * ad, pd1 = a1 * ad, pd2 = a2 * ad, pd3 = a3 * ad;
#pragma unroll
  for (int o = 16; o >= 1; o >>= 1) {
    ps0 += __shfl_xor(ps0, o); ps1 += __shfl_xor(ps1, o);
    ps2 += __shfl_xor(ps2, o); ps3 += __shfl_xor(ps3, o);
    pd0 += __shfl_xor(pd0, o); pd1 += __shfl_xor(pd1, o);
    pd2 += __shfl_xor(pd2, o); pd3 += __shfl_xor(pd3, o);
  }
  if ((col & 31) == 0) {
    const int head = col >> 5;
    const int b = r0 >> 11;
    const int n0 = (r0 & (BN - 1)) + rp;
    float* ss = ssrc + (b * HH + head) * BN;
    float* sd = sdst + (b * HH + head) * BN;
    ss[n0 + 0] = ps0; ss[n0 + 2] = ps1; ss[n0 + 4] = ps2; ss[n0 + 6] = ps3;
    sd[n0 + 0] = pd0; sd[n0 + 2] = pd1; sd[n0 + 4] = pd2; sd[n0 + 6] = pd3;
  }
}

// Kernel 2: one block per (b,i), b fast so 4 consecutive blocks share mask row i.
// Wave w = head w. Full softmax == reference top-k under fp32 underflow.
__global__ __launch_bounds__(256, 4) void gat_kernel(
    const float* __restrict__ hbuf, const float* __restrict__ ssrc,
    const float* __restrict__ sdst, const float* __restrict__ mask,
    float* __restrict__ outp, float* __restrict__ amean) {
  const int blk = blockIdx.x;
  const int b = blk & 3;
  const int i = blk >> 2;
  const int lane = threadIdx.x & 63;
  const int h = threadIdx.x >> 6;

  __shared__ float arow[BN];
  __shared__ int ls_j[HH][32];
  __shared__ float ls_a[HH][32];
  __shared__ int ls_cnt[HH];

  nfloat4* arow4 = (nfloat4*)arow;
#pragma unroll
  for (int t = 0; t < 2; ++t) arow4[threadIdx.x + t * 256] = (nfloat4)(0.f);
  if (lane == 0) ls_cnt[h] = 0;

  const float s_i = ssrc[(b * HH + h) * BN + i];
  const nfloat4* __restrict__ m4 = (const nfloat4*)(mask + (size_t)i * BN);
  const nfloat4* __restrict__ sd4 = (const nfloat4*)(sdst + (b * HH + h) * BN);

  float val[32];
  float vmax = -3.0e38f;
#pragma unroll
  for (int t = 0; t < 8; ++t) {
    const int idx = t * 64 + lane;
    const nfloat4 mm = m4[idx];
    const nfloat4 sv = sd4[idx];
#pragma unroll
    for (int u = 0; u < 4; ++u) {
      const float m = mm[u];
      const float s = s_i + sv[u];
      const float e = (s < 0.f) ? 0.2f * s : s;
      const float v = e * m + (1.0f - m) * NEGV;   // keep reference op order
      val[t * 4 + u] = v;
      vmax = fmaxf(vmax, v);
    }
  }
#pragma unroll
  for (int o = 32; o >= 1; o >>= 1) vmax = fmaxf(vmax, __shfl_xor(vmax, o));

  float lsum = 0.f;
#pragma unroll
  for (int t = 0; t < 32; ++t) {
    const float d = val[t] - vmax;
    float ex = 0.f;
    if (d > -30.f) ex = __expf(d);
    val[t] = ex;
    lsum += ex;
  }
  float sum = lsum;
#pragma unroll
  for (int o = 32; o >= 1; o >>= 1) sum += __shfl_xor(sum, o);
  const float inv = 1.0f / sum;

  __syncthreads();   // arow zeroing complete (latency hidden under score loop)

#pragma unroll
  for (int t = 0; t < 8; ++t) {
#pragma unroll
    for (int u = 0; u < 4; ++u) {
      const float ex = val[t * 4 + u];
      if (ex > 0.f) {
        const float a = ex * inv;
        const int j = t * 256 + lane * 4 + u;
        const int slot = atomicAdd(&ls_cnt[h], 1);
        if (slot < 32) { ls_j[h][slot] = j; ls_a[h][slot] = a; }
        atomicAdd(&arow[j], a * 0.25f);
      }
    }
  }

  // out[b,i,h,:] = sum_j alpha * h[b,j,h,:]
  int cnt = ls_cnt[h];          // same-wave ordering safe
  if (cnt > 32) cnt = 32;
  const int d = lane & 31;
  const int half = lane >> 5;
  float acc = 0.f;
  for (int k = half; k < cnt; k += 2) {
    const int jj = ls_j[h][k];
    acc = fmaf(ls_a[h][k], hbuf[((size_t)(b * BN + jj)) * KOUT + h * DD + d], acc);
  }
  acc += __shfl_xor(acc, 32);
  if (half == 0) outp[((size_t)(b * BN + i)) * KOUT + h * DD + d] = acc;

  __syncthreads();
  // stream completed alpha_mean row (write-once: nontemporal)
  nfloat4* __restrict__ arow_g = (nfloat4*)(amean + ((size_t)(b * BN + i)) * BN);
#pragma unroll
  for (int t = 0; t < 2; ++t)
    __builtin_nontemporal_store(arow4[threadIdx.x + t * 256], &arow_g[threadIdx.x + t * 256]);
}

extern "C" void kernel_launch(void* const* d_in, const int* in_sizes, int n_in,
                              void* d_out, int out_size, void* d_ws, size_t ws_size,
                              hipStream_t stream) {
  const float* x = (const float*)d_in[0];
  const float* W = (const float*)d_in[1];
  const float* a_src = (const float*)d_in[2];
  const float* a_dst = (const float*)d_in[3];
  const float* mask = (const float*)d_in[4];

  float* outp = (float*)d_out;                      // (B,N,H*D)
  float* amean = outp + (size_t)BB * BN * KOUT;     // (B,N,N)

  float* hbuf = (float*)d_ws;                       // (B,N,H*D) fp32
  float* ssrc = hbuf + (size_t)BB * BN * KOUT;      // (B,H,N)
  float* sdst = ssrc + (size_t)BB * HH * BN;        // (B,H,N)

  lin_kernel<<<(BB * BN) / 8, 256, 0, stream>>>(x, W, a_src, a_dst, hbuf, ssrc, sdst);
  gat_kernel<<<BB * BN, 256, 0, stream>>>(hbuf, ssrc, sdst, mask, outp, amean);
}